// Round 11
// baseline (779.903 us; speedup 1.0000x reference)
//
#include <hip/hip_runtime.h>

#define NE 32
#define NG 8
#define NK 4
#define ND 2048
#define NH 1024
#define NHS 4096
#define CAPE 1024
#define NT 4096

typedef float f32x4 __attribute__((ext_vector_type(4)));
typedef short s16x8 __attribute__((ext_vector_type(8)));

__device__ __forceinline__ short f2bf(float f) {
    return __builtin_bit_cast(short, (__bf16)f);
}
__device__ __forceinline__ float bf2f(short h) {
    return __builtin_bit_cast(float, ((unsigned)(unsigned short)h) << 16);
}

__device__ __forceinline__ void gload_lds16(const void* g, void* l) {
    __builtin_amdgcn_global_load_lds(
        (const __attribute__((address_space(1))) void*)g,
        (__attribute__((address_space(3))) void*)l, 16, 0, 0);
}

// ---------------------------------------------------------------------------
// Kernel 1: gating. One wave per token. fp32 logits, sigmoid, grouped top-k.
// ---------------------------------------------------------------------------
__global__ __launch_bounds__(256) void gate_kernel(
    const float* __restrict__ X, const float* __restrict__ Gw,
    const float* __restrict__ bias,
    int* __restrict__ topk_idx, float* __restrict__ topk_w)
{
    const int lane = threadIdx.x & 63;
    const int t = blockIdx.x * 4 + (threadIdx.x >> 6);
    const float* x = X + (size_t)t * ND;

    float xr[32];
#pragma unroll
    for (int i = 0; i < 32; i++) xr[i] = x[lane + i * 64];

    float scores[32];
#pragma unroll
    for (int e = 0; e < 32; e++) {
        const float* w = Gw + (size_t)e * ND;
        float a = 0.f;
#pragma unroll
        for (int i = 0; i < 32; i++) a = fmaf(xr[i], w[lane + i * 64], a);
#pragma unroll
        for (int s = 32; s > 0; s >>= 1) a += __shfl_xor(a, s);
        scores[e] = 1.0f / (1.0f + expf(-a));
    }

    float sc_c[32];
#pragma unroll
    for (int e = 0; e < 32; e++) sc_c[e] = scores[e] + bias[e];

    float gs[8];
#pragma unroll
    for (int g = 0; g < 8; g++) {
        float a = sc_c[4 * g], b = sc_c[4 * g + 1], c = sc_c[4 * g + 2], d = sc_c[4 * g + 3];
        float hi1 = fmaxf(a, b), lo1 = fminf(a, b);
        float hi2 = fmaxf(c, d), lo2 = fminf(c, d);
        float m1 = fmaxf(hi1, hi2);
        float m2 = fmaxf(fminf(hi1, hi2), fmaxf(lo1, lo2));
        gs[g] = m1 + m2;
    }

    unsigned gsel = 0;
#pragma unroll
    for (int it = 0; it < 4; it++) {
        int best = -1; float bv = -1e30f;
#pragma unroll
        for (int g = 0; g < 8; g++) {
            bool avail = !((gsel >> g) & 1);
            if (avail && gs[g] > bv) { bv = gs[g]; best = g; }
        }
        gsel |= 1u << best;
    }

    unsigned esel = 0;
    int idxs[4]; float wts[4];
#pragma unroll
    for (int it = 0; it < 4; it++) {
        int best = -1; float bv = -1e30f, braw = 0.f;
#pragma unroll
        for (int e = 0; e < 32; e++) {
            float mv = ((gsel >> (e >> 2)) & 1) ? sc_c[e] : 0.0f;
            bool avail = !((esel >> e) & 1);
            if (avail && mv > bv) { bv = mv; best = e; braw = scores[e]; }
        }
        esel |= 1u << best;
        idxs[it] = best; wts[it] = braw;
    }

    float s = wts[0] + wts[1] + wts[2] + wts[3] + 1e-20f;
    if (lane == 0) {
#pragma unroll
        for (int k = 0; k < 4; k++) {
            topk_idx[t * 4 + k] = idxs[k];
            topk_w[t * 4 + k] = wts[k] / s * 2.5f;
        }
    }
}

// ---------------------------------------------------------------------------
__global__ void zero_cnt(int* cnt) {
    if (threadIdx.x < NE) cnt[threadIdx.x] = 0;
}

__global__ void dispatch_kernel(const int* __restrict__ topk_idx,
                                int* __restrict__ cnt,
                                int* __restrict__ tok_list,
                                int* __restrict__ pos_list)
{
    int i = blockIdx.x * 256 + threadIdx.x;
    int e = topk_idx[i];
    int t = i >> 2;
    int pos = atomicAdd(&cnt[e], 1);
    pos_list[i] = pos;
    if (pos < CAPE) {
        tok_list[e * CAPE + pos] = t;
    }
}

// ---------------------------------------------------------------------------
// f32 -> bf16 bulk conversion (only used for X; weights consumed as f32)
// ---------------------------------------------------------------------------
__global__ __launch_bounds__(256) void cvt_f2bf(const float* __restrict__ in,
                                                short* __restrict__ out, int n8)
{
    int i = blockIdx.x * 256 + threadIdx.x;
    int stride = gridDim.x * 256;
    for (; i < n8; i += stride) {
        const f32x4* p = (const f32x4*)(in + (size_t)i * 8);
        f32x4 a = p[0], b = p[1];
        s16x8 h;
        h[0] = f2bf(a[0]); h[1] = f2bf(a[1]); h[2] = f2bf(a[2]); h[3] = f2bf(a[3]);
        h[4] = f2bf(b[0]); h[5] = f2bf(b[1]); h[6] = f2bf(b[2]); h[7] = f2bf(b[3]);
        *(s16x8*)(out + (size_t)i * 8) = h;
    }
}

// ---------------------------------------------------------------------------
// Combine: out[t] = shared_down[t] (already in out) + sum_k w_k * Ybuf[e_k,pos_k]
// ---------------------------------------------------------------------------
__global__ __launch_bounds__(256) void combine_kernel(
    const int* __restrict__ topk_idx, const float* __restrict__ topk_w,
    const int* __restrict__ pos_list,
    const short* __restrict__ Ybuf, float* __restrict__ out)
{
    const int t = blockIdx.x;
    const int d0 = threadIdx.x * 8;

    int e[NK], p[NK]; float w[NK];
#pragma unroll
    for (int k = 0; k < NK; k++) {
        e[k] = topk_idx[t * NK + k];
        p[k] = pos_list[t * NK + k];
        w[k] = topk_w[t * NK + k];
    }

    float* orow = out + (size_t)t * ND + d0;
    f32x4 o0 = *(f32x4*)(orow);
    f32x4 o1 = *(f32x4*)(orow + 4);

#pragma unroll
    for (int k = 0; k < NK; k++) {
        if (p[k] < CAPE) {
            s16x8 y = *(const s16x8*)(Ybuf + ((size_t)e[k] * CAPE + p[k]) * ND + d0);
            o0[0] = fmaf(w[k], bf2f(y[0]), o0[0]);
            o0[1] = fmaf(w[k], bf2f(y[1]), o0[1]);
            o0[2] = fmaf(w[k], bf2f(y[2]), o0[2]);
            o0[3] = fmaf(w[k], bf2f(y[3]), o0[3]);
            o1[0] = fmaf(w[k], bf2f(y[4]), o1[0]);
            o1[1] = fmaf(w[k], bf2f(y[5]), o1[1]);
            o1[2] = fmaf(w[k], bf2f(y[6]), o1[2]);
            o1[3] = fmaf(w[k], bf2f(y[7]), o1[3]);
        }
    }
    *(f32x4*)(orow) = o0;
    *(f32x4*)(orow + 4) = o1;
}

// ---------------------------------------------------------------------------
// 4-wave GEMM: 128x128, BK=32. A: quad-buffered LDS via gload_lds (4x8KB).
// B: f32 direct from HBM, 4-deep reg pipeline (br0..br3) -> cvt -> swizzled
// ds_write (2x8KB LDS dbuf). 48 KB LDS total -> 3 blocks/CU.
// Ledger (per iter T): issue STAGE_A(T+3)[2]; queue=[B(T+1)4,A(T+1)2,B(T+2)4,
// A(T+2)2,B(T+3)4,A(T+3)2]=18; vmcnt(12) retires {B(T+1),A(T+1)} exactly.
// B loaded at T-3, consumed at T+... -> 3 iters of HBM-latency cover.
// Swizzle (both sides): phys 16B slot = logical ^ (row&3); A source inverse-
// permuted (gload_lds linear dest), B permuted at ds_write; reads use same XOR.
// MODE 0: routed up   (A = Xbf gathered,  B = up_w[e],  out = relu2 -> Hbuf)
// MODE 1: routed down (A = Hbuf[e],       B = dn_w[e],  out = Ybuf bf16)
// MODE 2: shared up   (A = Xbf,           B = sup,      out = relu2 -> Sbuf)
// MODE 3: shared down (A = Sbuf,          B = sdn,      out = f32 write)
// ---------------------------------------------------------------------------
template <int MODE>
__global__ __launch_bounds__(256, 3) void moe_gemm5(
    const short* __restrict__ Abase, const float* __restrict__ Bbase,
    const int* __restrict__ cnt, const int* __restrict__ tok_list,
    short* __restrict__ Hout, float* __restrict__ out)
{
    constexpr int K = (MODE == 0) ? ND : (MODE == 1) ? NH : (MODE == 2) ? ND : NHS;
    constexpr int NTILES = K / 32;   // 64, 32, 64, 128 — all divisible by 4

    const int e = blockIdx.z;
    const int m0 = blockIdx.y * 128, n0 = blockIdx.x * 128;

    int mcnt = 0;
    if constexpr (MODE == 0 || MODE == 1) {
        mcnt = min(cnt[e], CAPE);
        if (m0 >= mcnt) return;
    }

    __shared__ short As[4][128 * 32];   // 32 KB
    __shared__ short Bs[2][128 * 32];   // 16 KB

    const int tid = threadIdx.x;
    const int lane = tid & 63;
    const int wave = tid >> 6;
    const int wr = wave >> 1, wc = wave & 1;

    const short* Ab = Abase;
    const float* Bb = Bbase;
    if constexpr (MODE == 0) Bb += (size_t)e * NH * ND;
    if constexpr (MODE == 1) { Ab += (size_t)e * CAPE * NH; Bb += (size_t)e * ND * NH; }

    // ---- A staging: 2 ops/tile; op o: row = o*64 + tid>>2, phys slot tid&3 ----
    const int arow = tid >> 2;                  // 0..63
    const int aslot = tid & 3;
    const int gcolA = (aslot ^ (arow & 3)) * 8; // inverse-swizzled source col
    const short* asrc[2];
    int dstA[2];
#pragma unroll
    for (int o = 0; o < 2; o++) {
        int r = o * 64 + arow;
        if constexpr (MODE == 0) {
            int gr = min(m0 + r, mcnt - 1);
            int tok = tok_list[e * CAPE + gr];
            asrc[o] = Abase + (size_t)tok * ND + gcolA;
        } else if constexpr (MODE == 1) {
            int gr = min(m0 + r, mcnt - 1);
            asrc[o] = Ab + (size_t)gr * NH + gcolA;
        } else if constexpr (MODE == 2) {
            asrc[o] = Abase + (size_t)(m0 + r) * ND + gcolA;
        } else {
            asrc[o] = Abase + (size_t)(m0 + r) * NHS + gcolA;
        }
        dstA[o] = o * 2048 + wave * 512;        // linear dest (+lane*8 by HW)
    }

    // ---- B staging: thread = (row = tid>>1, half = tid&1), 64 B f32 ----
    const int brow = tid >> 1;                  // 0..127
    const int bhalf = tid & 1;
    const float* bsrcp = Bb + (size_t)(n0 + brow) * K + bhalf * 16;
    const int bd0 = brow * 32 + (((2 * bhalf)     ^ (brow & 3)) * 8);
    const int bd1 = brow * 32 + (((2 * bhalf + 1) ^ (brow & 3)) * 8);

    auto STAGE_A = [&](int tt) {
        const int ko = (tt < NTILES ? tt : NTILES - 1) * 32;
        short* Ad = As[tt & 3];
#pragma unroll
        for (int o = 0; o < 2; o++) gload_lds16(asrc[o] + ko, Ad + dstA[o]);
    };
    auto BLOAD = [&](int tt, f32x4* regs) {
        const int ko = (tt < NTILES ? tt : NTILES - 1) * 32;
#pragma unroll
        for (int i = 0; i < 4; i++) regs[i] = *(const f32x4*)(bsrcp + ko + i * 4);
    };
    auto BWRITE = [&](const f32x4* regs, int par) {
        short* Bd = Bs[par];
        s16x8 h0, h1;
        h0[0] = f2bf(regs[0][0]); h0[1] = f2bf(regs[0][1]);
        h0[2] = f2bf(regs[0][2]); h0[3] = f2bf(regs[0][3]);
        h0[4] = f2bf(regs[1][0]); h0[5] = f2bf(regs[1][1]);
        h0[6] = f2bf(regs[1][2]); h0[7] = f2bf(regs[1][3]);
        h1[0] = f2bf(regs[2][0]); h1[1] = f2bf(regs[2][1]);
        h1[2] = f2bf(regs[2][2]); h1[3] = f2bf(regs[2][3]);
        h1[4] = f2bf(regs[3][0]); h1[5] = f2bf(regs[3][1]);
        h1[6] = f2bf(regs[3][2]); h1[7] = f2bf(regs[3][3]);
        *(s16x8*)(Bd + bd0) = h0;
        *(s16x8*)(Bd + bd1) = h1;
    };

    // ---- fragment read offsets ----
    const int r16 = lane & 15;
    const int ks = lane >> 4;
    const int physA = (ks ^ (r16 & 3)) * 8;
    int offA[4], offB[4];
#pragma unroll
    for (int m = 0; m < 4; m++)
        offA[m] = (wr * 64 + m * 16 + r16) * 32 + physA;
#pragma unroll
    for (int n = 0; n < 4; n++)
        offB[n] = (wc * 64 + n * 16 + r16) * 32 + physA;

    f32x4 acc[4][4] = {};
    f32x4 br0[4], br1[4], br2[4], br3[4];   // B reg pipeline (static parity)

    // ---- prologue: build steady-state queue [B1,A1,B2,A2,B3] = 16 ----
    STAGE_A(0); BLOAD(0, br0);
    BLOAD(1, br1); STAGE_A(1);
    BLOAD(2, br2); STAGE_A(2);
    BLOAD(3, br3);
    asm volatile("s_waitcnt vmcnt(16)" ::: "memory");   // retire A0, B0
    __builtin_amdgcn_sched_barrier(0);
    BWRITE(br0, 0);
    asm volatile("s_waitcnt lgkmcnt(0)" ::: "memory");
    __builtin_amdgcn_sched_barrier(0);

#define GEMM_ITER(T, BRW, BRL)                                                  \
    {                                                                           \
        __builtin_amdgcn_s_barrier();                                           \
        __builtin_amdgcn_sched_barrier(0);                                      \
        STAGE_A((T) + 3);                                                       \
        asm volatile("s_waitcnt vmcnt(12)" ::: "memory");                       \
        __builtin_amdgcn_sched_barrier(0);                                      \
        BWRITE(BRW, ((T) + 1) & 1);                                             \
        BLOAD((T) + 4, BRL);                                                    \
        const short* At = As[(T) & 3];                                          \
        const short* Bt = Bs[(T) & 1];                                          \
        s16x8 af[4], bf[4];                                                     \
        _Pragma("unroll")                                                       \
        for (int m = 0; m < 4; m++) af[m] = *(const s16x8*)(At + offA[m]);      \
        _Pragma("unroll")                                                       \
        for (int n = 0; n < 4; n++) bf[n] = *(const s16x8*)(Bt + offB[n]);      \
        asm volatile("s_waitcnt lgkmcnt(0)" ::: "memory");                      \
        __builtin_amdgcn_sched_barrier(0);                                      \
        __builtin_amdgcn_s_setprio(1);                                          \
        _Pragma("unroll")                                                       \
        for (int m = 0; m < 4; m++)                                             \
            _Pragma("unroll")                                                   \
            for (int n = 0; n < 4; n++)                                         \
                acc[m][n] = __builtin_amdgcn_mfma_f32_16x16x32_bf16(            \
                    af[m], bf[n], acc[m][n], 0, 0, 0);                          \
        __builtin_amdgcn_s_setprio(0);                                          \
    }

    for (int t = 0; t < NTILES; t += 4) {
        GEMM_ITER(t + 0, br1, br0);
        GEMM_ITER(t + 1, br2, br1);
        GEMM_ITER(t + 2, br3, br2);
        GEMM_ITER(t + 3, br0, br3);
    }
#undef GEMM_ITER

    // ---- epilogue ----  C mapping: col = lane&15, row = (lane>>4)*4 + reg
    const int r0 = (lane >> 4) * 4;
    const int cc = lane & 15;

    if constexpr (MODE == 0 || MODE == 2) {
#pragma unroll
        for (int i = 0; i < 4; i++)
#pragma unroll
            for (int j = 0; j < 4; j++)
#pragma unroll
                for (int v = 0; v < 4; v++) {
                    int row = wr * 64 + i * 16 + r0 + v;
                    int col = wc * 64 + j * 16 + cc;
                    float val = acc[i][j][v];
                    float r = fmaxf(val, 0.f);
                    val = r * r;
                    if constexpr (MODE == 0)
                        Hout[((size_t)e * CAPE + m0 + row) * NH + (n0 + col)] = f2bf(val);
                    else
                        Hout[(size_t)(m0 + row) * NHS + (n0 + col)] = f2bf(val);
                }
    } else if constexpr (MODE == 3) {
#pragma unroll
        for (int i = 0; i < 4; i++)
#pragma unroll
            for (int j = 0; j < 4; j++)
#pragma unroll
                for (int v = 0; v < 4; v++) {
                    int row = wr * 64 + i * 16 + r0 + v;
                    int col = wc * 64 + j * 16 + cc;
                    out[(size_t)(m0 + row) * ND + (n0 + col)] = acc[i][j][v];
                }
    } else {  // MODE 1: bf16 store to Ybuf, valid rows only
#pragma unroll
        for (int i = 0; i < 4; i++)
#pragma unroll
            for (int v = 0; v < 4; v++) {
                int row = wr * 64 + i * 16 + r0 + v;
                int grow = m0 + row;
                if (grow < mcnt) {
#pragma unroll
                    for (int j = 0; j < 4; j++) {
                        int col = wc * 64 + j * 16 + cc;
                        Hout[((size_t)e * CAPE + grow) * ND + (n0 + col)] = f2bf(acc[i][j][v]);
                    }
                }
            }
    }
}

// ---------------------------------------------------------------------------
extern "C" void kernel_launch(void* const* d_in, const int* in_sizes, int n_in,
                              void* d_out, int out_size, void* d_ws, size_t ws_size,
                              hipStream_t stream) {
    const float* X    = (const float*)d_in[0];
    const float* Gw   = (const float*)d_in[1];
    const float* bias = (const float*)d_in[2];
    const float* up_w = (const float*)d_in[3];
    const float* dn_w = (const float*)d_in[4];
    const float* sup  = (const float*)d_in[5];
    const float* sdn  = (const float*)d_in[6];
    float* out = (float*)d_out;

    char* ws = (char*)d_ws;
    size_t off = 0;
    auto alloc = [&](size_t bytes) -> void* {
        off = (off + 255) & ~(size_t)255;
        void* p = ws + off;
        off += bytes;
        return p;
    };
    int*   cnt      = (int*)  alloc(NE * 4);
    int*   topk_idx = (int*)  alloc((size_t)NT * NK * 4);
    float* topk_w   = (float*)alloc((size_t)NT * NK * 4);
    int*   pos_list = (int*)  alloc((size_t)NT * NK * 4);
    int*   tok_list = (int*)  alloc((size_t)NE * CAPE * 4);
    short* Hbuf     = (short*)alloc((size_t)NE * CAPE * NH * 2);   // 64 MB
    short* Sbuf     = (short*)alloc((size_t)NT * NHS * 2);         // 32 MB
    short* Xbf      = (short*)alloc((size_t)NT * ND * 2);          // 16 MB
    short* Ybuf     = (short*)alloc((size_t)NE * CAPE * ND * 2);   // 128 MB

    gate_kernel<<<dim3(NT / 4), dim3(256), 0, stream>>>(X, Gw, bias, topk_idx, topk_w);
    zero_cnt<<<dim3(1), dim3(64), 0, stream>>>(cnt);
    dispatch_kernel<<<dim3(NT * NK / 256), dim3(256), 0, stream>>>(
        topk_idx, cnt, tok_list, pos_list);

    // only X needs pre-conversion (weights consumed as f32 in-GEMM)
    cvt_f2bf<<<dim3(1024), dim3(256), 0, stream>>>(X, Xbf, NT * ND / 8);

    // routed up: X gathered -> Hbuf
    moe_gemm5<0><<<dim3(NH / 128, CAPE / 128, NE), dim3(256), 0, stream>>>(
        Xbf, up_w, cnt, tok_list, Hbuf, nullptr);
    // shared up: X -> Sbuf
    moe_gemm5<2><<<dim3(NHS / 128, NT / 128, 1), dim3(256), 0, stream>>>(
        Xbf, sup, nullptr, nullptr, Sbuf, nullptr);
    // shared down: Sbuf -> out (f32 write; MUST precede combine)
    moe_gemm5<3><<<dim3(ND / 128, NT / 128, 1), dim3(256), 0, stream>>>(
        Sbuf, sdn, nullptr, nullptr, nullptr, out);
    // routed down: Hbuf -> Ybuf
    moe_gemm5<1><<<dim3(ND / 128, CAPE / 128, NE), dim3(256), 0, stream>>>(
        Hbuf, dn_w, cnt, tok_list, Ybuf, nullptr);
    // combine: out += sum_k w_k * Ybuf[e_k, pos_k]
    combine_kernel<<<dim3(NT), dim3(256), 0, stream>>>(
        topk_idx, topk_w, pos_list, Ybuf, out);
}